// Round 8
// baseline (239.401 us; speedup 1.0000x reference)
//
#include <hip/hip_runtime.h>

// ---------------------------------------------------------------------------
// MultiHeadAttention (B=2,S=2048,H=16,DH=64,D=1024), fp32 in/out, fp16 MFMA.
// Pipeline: prep -> QKV gemm -> memset(Ob,Lb) -> attn v8 -> gemmO(+normalize).
// attn v8: NO LDS STAGING, NO K-LOOP BARRIERS. 4 waves = (kv-half, q-half);
//   K/V fragments loaded straight from global (coalesced dwordx4, L1/L2-hot);
//   fixed-shift softmax => kv-split additive; LDS only for wave-private P
//   transpose + end-of-block O combine; atomicAdd fp32 partials (v7 path).
//   Theory: v7 was LDS-pipe-bound (~106 KB/tile-unit); v8 moves ~13 KB.
// MFMA 16x16x32 f16 layouts (verified rounds 1-7):
//   A: m=lane&15, k=quad*8+j   B: n=lane&15, k=quad*8+j
//   C/D: col(n)=lane&15, row(m)=quad*4+reg
// ---------------------------------------------------------------------------

typedef _Float16 f16x8 __attribute__((ext_vector_type(8)));
typedef float f32x4 __attribute__((ext_vector_type(4)));

#define GLD_LDS16(g, l)                                                        \
  __builtin_amdgcn_global_load_lds(                                            \
      (__attribute__((address_space(1))) const unsigned int*)(g),              \
      (__attribute__((address_space(3))) unsigned int*)(l), 16, 0, 0)

static constexpr int Sdim = 2048;
static constexpr int Ddim = 1024;
static constexpr int NH = 16;
static constexpr int DH = 64;
static constexpr int Mrows = 4096;  // B*S
static constexpr int CT = 8;        // KV tiles per attn chunk

// Q prescale: 1/sqrt(64) * log2(e), so P = exp2(S' - SHIFT) natively.
static constexpr float QSCALE = 0.125f * 1.44269504f;
static constexpr float SHIFT = 4.0f;

// ------------------- prep: X fp32->fp16  +  W [K,N]->fp16 [N,K] ------------
struct WtArgs {
  const float *s0, *s1, *s2, *s3;
  _Float16 *d0, *d1, *d2, *d3;
};

__global__ __launch_bounds__(256) void prep(const float* __restrict__ X,
                                            _Float16* __restrict__ Y, WtArgs a) {
  __shared__ _Float16 L[64 * 72];
  const int bid = blockIdx.x, t = threadIdx.x;
  if (bid < 2048) {  // xcvt: 4096x1024 fp32 -> fp16
    size_t i = ((size_t)bid * 256 + t) * 8;
    float4 f0 = *(const float4*)(X + i);
    float4 f1 = *(const float4*)(X + i + 4);
    alignas(16) _Float16 h[8] = {(_Float16)f0.x, (_Float16)f0.y, (_Float16)f0.z,
                                 (_Float16)f0.w, (_Float16)f1.x, (_Float16)f1.y,
                                 (_Float16)f1.z, (_Float16)f1.w};
    *(uint4*)(Y + i) = *(const uint4*)h;
    return;
  }
  const int w = bid - 2048, z = w >> 8, rem = w & 255;
  const float* src = z == 0 ? a.s0 : z == 1 ? a.s1 : z == 2 ? a.s2 : a.s3;
  _Float16* dst = z == 0 ? a.d0 : z == 1 ? a.d1 : z == 2 ? a.d2 : a.d3;
  const int k0 = (rem & 15) * 64, n0 = (rem >> 4) * 64;
#pragma unroll
  for (int i = 0; i < 4; ++i) {
    int c = i * 256 + t;  // 1024 chunks of 4 floats
    int row = c >> 4, cc = c & 15;
    float4 f = *(const float4*)&src[(size_t)(k0 + row) * Ddim + n0 + cc * 4];
    L[(cc * 4 + 0) * 72 + row] = (_Float16)f.x;
    L[(cc * 4 + 1) * 72 + row] = (_Float16)f.y;
    L[(cc * 4 + 2) * 72 + row] = (_Float16)f.z;
    L[(cc * 4 + 3) * 72 + row] = (_Float16)f.w;
  }
  __syncthreads();
#pragma unroll
  for (int i = 0; i < 2; ++i) {
    int c = i * 256 + t;  // 512 chunks of 8 halves
    int n = c >> 3, cc = c & 7;
    *(uint4*)&dst[(size_t)(n0 + n) * Ddim + k0 + cc * 8] =
        *(const uint4*)&L[n * 72 + cc * 8];
  }
}

// ----------------------- 128x128 GEMM (QKV only) ---------------------------
struct GemmArgs {
  const _Float16* A;
  const _Float16 *Bt0, *Bt1, *Bt2;
  const float *b0, *b1, *b2;
  void *o0, *o1, *o2;
};

__global__ __launch_bounds__(256) void gemmQKV(GemmArgs g) {
  constexpr int K = 1024;
  __shared__ _Float16 As[128 * 32];
  __shared__ _Float16 Bs[128 * 32];
  const int z = blockIdx.z;
  const _Float16* A = g.A;
  const _Float16* Bt = z == 0 ? g.Bt0 : z == 1 ? g.Bt1 : g.Bt2;
  const float* bias = z == 0 ? g.b0 : z == 1 ? g.b1 : g.b2;
  void* out = z == 0 ? g.o0 : z == 1 ? g.o1 : g.o2;
  const int m0 = blockIdx.x * 128, n0 = blockIdx.y * 128;
  const int t = threadIdx.x, lane = t & 63, wv = t >> 6;
  const int wm = wv >> 1, wn = wv & 1, quad = lane >> 4, r = lane & 15;

  const int c0 = wv * 64 + lane, c1 = c0 + 256;
  const _Float16* ga0 = A + (size_t)(m0 + (c0 >> 2)) * K + (c0 & 3) * 8;
  const _Float16* ga1 = A + (size_t)(m0 + (c1 >> 2)) * K + (c1 & 3) * 8;
  const _Float16* gb0 = Bt + (size_t)(n0 + (c0 >> 2)) * K + (c0 & 3) * 8;
  const _Float16* gb1 = Bt + (size_t)(n0 + (c1 >> 2)) * K + (c1 & 3) * 8;
  char* lA0 = (char*)As + (wv * 64) * 16;
  char* lA1 = (char*)As + (256 + wv * 64) * 16;
  char* lB0 = (char*)Bs + (wv * 64) * 16;
  char* lB1 = (char*)Bs + (256 + wv * 64) * 16;

  f32x4 acc[4][4] = {};
  for (int kt = 0; kt < K; kt += 32) {
    GLD_LDS16(ga0 + kt, lA0);
    GLD_LDS16(ga1 + kt, lA1);
    GLD_LDS16(gb0 + kt, lB0);
    GLD_LDS16(gb1 + kt, lB1);
    __syncthreads();
    f16x8 af[4], bf[4];
#pragma unroll
    for (int mi = 0; mi < 4; ++mi)
      af[mi] = *(const f16x8*)&As[(wm * 64 + mi * 16 + r) * 32 + quad * 8];
#pragma unroll
    for (int ni = 0; ni < 4; ++ni)
      bf[ni] = *(const f16x8*)&Bs[(wn * 64 + ni * 16 + r) * 32 + quad * 8];
#pragma unroll
    for (int mi = 0; mi < 4; ++mi)
#pragma unroll
      for (int ni = 0; ni < 4; ++ni)
        acc[mi][ni] = __builtin_amdgcn_mfma_f32_16x16x32_f16(af[mi], bf[ni],
                                                             acc[mi][ni], 0, 0, 0);
    __syncthreads();
  }

  const float scale = (z == 0) ? QSCALE : 1.0f;
  float bv[4];
#pragma unroll
  for (int ni = 0; ni < 4; ++ni) bv[ni] = bias[n0 + wn * 64 + ni * 16 + r];
#pragma unroll
  for (int mi = 0; mi < 4; ++mi) {
#pragma unroll
    for (int ni = 0; ni < 4; ++ni) {
      const int n = n0 + wn * 64 + ni * 16 + r;
      if (z == 2) {
        alignas(8) _Float16 h4[4];
#pragma unroll
        for (int reg = 0; reg < 4; ++reg)
          h4[reg] = (_Float16)(acc[mi][ni][reg] + bv[ni]);
        const int m = m0 + wm * 64 + mi * 16 + quad * 4;
        const int b = m >> 11, s = m & 2047, h = n >> 6, dh = n & 63;
        *(uint2*)&((_Float16*)out)[((size_t)(b * NH + h) * DH + dh) * Sdim + s] =
            *(const uint2*)h4;
      } else {
#pragma unroll
        for (int reg = 0; reg < 4; ++reg) {
          const int m = m0 + wm * 64 + mi * 16 + quad * 4 + reg;
          const float v = (acc[mi][ni][reg] + bv[ni]) * scale;
          const int b = m >> 11, s = m & 2047, h = n >> 6, dh = n & 63;
          ((_Float16*)out)[(((size_t)(b * NH + h) * Sdim + s) << 6) + dh] =
              (_Float16)v;
        }
      }
    }
  }
}

// ------------------------- flash attention v8 ------------------------------
// grid 2560, 256 thr. Block = KV chunk (<=8 tiles) of one (bh, qt).
// Wave wv=(i,j): i=wv&1 kv-half, j=wv>>1 q-half. No staging, no K-loop
// barriers: K A-frags & V B-frags direct from global (dwordx4, L1/L2-hot).
// LDS: per-wave P transpose (2.5KB) + end-of-block O combine (16KB, reused).
__global__ __launch_bounds__(256) void attn(const _Float16* __restrict__ Q,
                                            const _Float16* __restrict__ Kk,
                                            const _Float16* __restrict__ Vt,
                                            float* __restrict__ Ob,
                                            float* __restrict__ Lb) {
  constexpr int LP = 40;  // Pw padded stride (halves)
  __shared__ char smem[16384];  // Pw: 4 x 2560B (loop) ; Oex: 2 x 8KB (epilogue)
  const int id = blockIdx.x, xcd = id & 7, jid = id >> 3;
  const int b2 = jid / 80, jj = jid - 80 * b2;
  int qt, c;
  if (jj < 8) {
    qt = jj; c = 0;
  } else if (jj < 24) {
    qt = 8 + ((jj - 8) >> 1); c = (jj - 8) & 1;
  } else if (jj < 48) {
    qt = 16 + (jj - 24) / 3; c = (jj - 24) % 3;
  } else {
    qt = 24 + ((jj - 48) >> 2); c = (jj - 48) & 3;
  }
  const int bh = xcd + 8 * b2;
  const int t = threadIdx.x, lane = t & 63, wv = t >> 6;
  const int i = wv & 1, jq = wv >> 1;
  const int quad = lane >> 4, r = lane & 15;
  const int q0 = qt * 64;
  const int it0 = c * CT;
  const int itn = (it0 + CT < qt + 1) ? it0 + CT : qt + 1;
  const _Float16* Kg = Kk + (size_t)bh * Sdim * DH;  // [S, 64]
  const _Float16* Vg = Vt + (size_t)bh * DH * Sdim;  // [64, S]
  _Float16* Pw = (_Float16*)(smem + wv * 2560);

  // Q B-frags: qf[ni][ks], q = q0 + jq*32 + ni*16 + r
  const _Float16* Qbase = Q + ((size_t)bh * Sdim + q0 + jq * 32 + r) * DH;
  f16x8 qf[2][2];
  qf[0][0] = *(const f16x8*)(Qbase + quad * 8);
  qf[0][1] = *(const f16x8*)(Qbase + 32 + quad * 8);
  qf[1][0] = *(const f16x8*)(Qbase + 16 * DH + quad * 8);
  qf[1][1] = *(const f16x8*)(Qbase + 16 * DH + 32 + quad * 8);

  // per-tile global fragment pointers (16B-aligned, coalesced)
  const _Float16* kbase = Kg + (size_t)(it0 * 64 + i * 32 + r) * DH + quad * 8;
  const _Float16* vbase = Vg + (size_t)r * Sdim + it0 * 64 + i * 32 + quad * 8;

  float l2[2] = {0.f, 0.f};
  f32x4 oacc[2][4] = {};  // [mi: q16][ni: dh16]

  for (int it = it0; it < itn; ++it) {
    // K A-frags kf[mi][ks] (kv = i*32+mi*16+r), V B-frags vf[ni] (dh=ni*16+r)
    f16x8 kf[2][2], vf[4];
    kf[0][0] = *(const f16x8*)(kbase);
    kf[0][1] = *(const f16x8*)(kbase + 32);
    kf[1][0] = *(const f16x8*)(kbase + 16 * DH);
    kf[1][1] = *(const f16x8*)(kbase + 16 * DH + 32);
    vf[0] = *(const f16x8*)(vbase);
    vf[1] = *(const f16x8*)(vbase + 16 * Sdim);
    vf[2] = *(const f16x8*)(vbase + 32 * Sdim);
    vf[3] = *(const f16x8*)(vbase + 48 * Sdim);
    kbase += 64 * DH;
    vbase += 64;

    // S^T(kv32 x q32) = K Q^T ; sacc[mi][ni]: kv=i*32+mi*16+quad*4+reg, q=jq*32+ni*16+r
    f32x4 sacc[2][2] = {};
#pragma unroll
    for (int ks = 0; ks < 2; ++ks)
#pragma unroll
      for (int mi = 0; mi < 2; ++mi)
#pragma unroll
        for (int ni = 0; ni < 2; ++ni)
          sacc[mi][ni] = __builtin_amdgcn_mfma_f32_16x16x32_f16(
              kf[mi][ks], qf[ni][ks], sacc[mi][ni], 0, 0, 0);

    if (it == qt) {  // diagonal tile mask (local indices)
#pragma unroll
      for (int mi = 0; mi < 2; ++mi)
#pragma unroll
        for (int ni = 0; ni < 2; ++ni)
#pragma unroll
          for (int reg = 0; reg < 4; ++reg)
            if (i * 32 + mi * 16 + quad * 4 + reg > jq * 32 + ni * 16 + r)
              sacc[mi][ni][reg] = -1e30f;
    }

    // P = exp2(S'-SHIFT); transpose into Pw[q_loc32][kv_loc32] via C-layout
    float lp[2] = {0.f, 0.f};
#pragma unroll
    for (int mi = 0; mi < 2; ++mi)
#pragma unroll
      for (int ni = 0; ni < 2; ++ni) {
        const float p0 = exp2f(sacc[mi][ni][0] - SHIFT);
        const float p1 = exp2f(sacc[mi][ni][1] - SHIFT);
        const float p2 = exp2f(sacc[mi][ni][2] - SHIFT);
        const float p3 = exp2f(sacc[mi][ni][3] - SHIFT);
        lp[ni] += (p0 + p1) + (p2 + p3);
        int2 st;
        st.x = __builtin_bit_cast(int, __builtin_amdgcn_cvt_pkrtz(p0, p1));
        st.y = __builtin_bit_cast(int, __builtin_amdgcn_cvt_pkrtz(p2, p3));
        *(int2*)&Pw[(ni * 16 + r) * LP + mi * 16 + quad * 4] = st;
      }
#pragma unroll
    for (int ni = 0; ni < 2; ++ni) {
      float s = lp[ni];
      s += __shfl_xor(s, 16, 64);
      s += __shfl_xor(s, 32, 64);
      l2[ni] += s;
    }

    // O(q32 x dh64) += P V : A = Pw rows (m=q, wave-private), B = vf (n=dh),
    // k = this wave's 32 kv.
#pragma unroll
    for (int mi = 0; mi < 2; ++mi) {
      const f16x8 ap = *(const f16x8*)&Pw[(mi * 16 + r) * LP + quad * 8];
#pragma unroll
      for (int ni = 0; ni < 4; ++ni)
        oacc[mi][ni] = __builtin_amdgcn_mfma_f32_16x16x32_f16(ap, vf[ni],
                                                              oacc[mi][ni], 0, 0, 0);
    }
  }

  // l partials: both kv-half waves add (additive under fixed shift)
  if (quad == 0) {
#pragma unroll
    for (int ni = 0; ni < 2; ++ni)
      atomicAdd(&Lb[(size_t)bh * Sdim + q0 + jq * 32 + ni * 16 + r], l2[ni]);
  }

  // O combine: wave i=1 parks its partial in LDS; wave i=0 adds + atomics.
  float* Oex = (float*)smem + jq * 2048;
  __syncthreads();  // all Pw reads done (smem reuse)
  if (i == 1) {
#pragma unroll
    for (int mi = 0; mi < 2; ++mi)
#pragma unroll
      for (int ni = 0; ni < 4; ++ni)
        *(f32x4*)&Oex[(mi * 4 + ni) * 256 + lane * 4] = oacc[mi][ni];
  }
  __syncthreads();
  if (i == 0) {
    const int b = bh >> 4, h = bh & 15;
    float* obase = Ob + ((size_t)b * Sdim + q0 + jq * 32) * Ddim + h * DH;
#pragma unroll
    for (int mi = 0; mi < 2; ++mi)
#pragma unroll
      for (int ni = 0; ni < 4; ++ni) {
        const f32x4 other = *(const f32x4*)&Oex[(mi * 4 + ni) * 256 + lane * 4];
#pragma unroll
        for (int reg = 0; reg < 4; ++reg)
          atomicAdd(obase + (size_t)(mi * 16 + quad * 4 + reg) * Ddim + ni * 16 + r,
                    oacc[mi][ni][reg] + other[reg]);
      }
  }
}

// ------------- O-proj GEMM (64x128 tiles) with fused normalize -------------
// A = Ob fp32 [4096,1024] / l (per row m and head h=k>>6), cvt fp16 in regs.
__global__ __launch_bounds__(256) void gemmO(const float* __restrict__ Ob,
                                             const float* __restrict__ Lb,
                                             const _Float16* __restrict__ Bt,
                                             const float* __restrict__ bias,
                                             float* __restrict__ out) {
  constexpr int K = 1024;
  __shared__ _Float16 As[64 * 32];
  __shared__ _Float16 Bs[128 * 32];
  const int m0 = blockIdx.x * 64, n0 = blockIdx.y * 128;
  const int t = threadIdx.x, lane = t & 63, wv = t >> 6;
  const int quad = lane >> 4, r = lane & 15;

  const int arow = m0 + (t >> 2), koff = (t & 3) * 8;
  const int ab = arow >> 11, as = arow & 2047;
  const float* ga = Ob + (size_t)arow * K + koff;
  const float* lrow = Lb + (size_t)(ab * NH) * Sdim + as;  // + h*Sdim
  const int c1 = t + 256;
  const _Float16* gb0 = Bt + (size_t)(n0 + (t >> 2)) * K + (t & 3) * 8;
  const _Float16* gb1 = Bt + (size_t)(n0 + (c1 >> 2)) * K + (c1 & 3) * 8;
  char* lB0 = (char*)Bs + t * 16;
  char* lB1 = (char*)Bs + (256 + t) * 16;

  f32x4 acc[4][2] = {};
  for (int kt = 0; kt < K; kt += 32) {
    GLD_LDS16(gb0 + kt, lB0);
    GLD_LDS16(gb1 + kt, lB1);
    // A: load fp32 x8, normalize by 1/l(m, h), cvt fp16, ds_write_b128
    const int h = (kt + koff) >> 6;
    const float rl = 1.0f / lrow[(size_t)h * Sdim];
    float4 f0 = *(const float4*)(ga + kt);
    float4 f1 = *(const float4*)(ga + kt + 4);
    int4 ah;
    ah.x = __builtin_bit_cast(int, __builtin_amdgcn_cvt_pkrtz(f0.x * rl, f0.y * rl));
    ah.y = __builtin_bit_cast(int, __builtin_amdgcn_cvt_pkrtz(f0.z * rl, f0.w * rl));
    ah.z = __builtin_bit_cast(int, __builtin_amdgcn_cvt_pkrtz(f1.x * rl, f1.y * rl));
    ah.w = __builtin_bit_cast(int, __builtin_amdgcn_cvt_pkrtz(f1.z * rl, f1.w * rl));
    *(int4*)((char*)As + t * 16) = ah;
    __syncthreads();
    f16x8 af[4], bf[2];
#pragma unroll
    for (int mi = 0; mi < 4; ++mi)
      af[mi] = *(const f16x8*)&As[(mi * 16 + r) * 32 + quad * 8];
#pragma unroll
    for (int ni = 0; ni < 2; ++ni)
      bf[ni] = *(const f16x8*)&Bs[(wv * 32 + ni * 16 + r) * 32 + quad * 8];
#pragma unroll
    for (int mi = 0; mi < 4; ++mi)
#pragma unroll
      for (int ni = 0; ni < 2; ++ni)
        acc[mi][ni] = __builtin_amdgcn_mfma_f32_16x16x32_f16(af[mi], bf[ni],
                                                             acc[mi][ni], 0, 0, 0);
    __syncthreads();
  }

  const float bv0 = bias[n0 + wv * 32 + r];
  const float bv1 = bias[n0 + wv * 32 + 16 + r];
#pragma unroll
  for (int mi = 0; mi < 4; ++mi)
#pragma unroll
    for (int reg = 0; reg < 4; ++reg) {
      const int m = m0 + mi * 16 + quad * 4 + reg;
      float* orow = out + (size_t)m * Ddim + n0 + wv * 32 + r;
      orow[0] = acc[mi][0][reg] + bv0;
      orow[16] = acc[mi][1][reg] + bv1;
    }
}

// ------------------------------ launcher -----------------------------------
extern "C" void kernel_launch(void* const* d_in, const int* in_sizes, int n_in,
                              void* d_out, int out_size, void* d_ws,
                              size_t ws_size, hipStream_t stream) {
  const float* hid = (const float*)d_in[0];
  const float* Wq = (const float*)d_in[1];
  const float* bq = (const float*)d_in[2];
  const float* Wk = (const float*)d_in[3];
  const float* bk = (const float*)d_in[4];
  const float* Wv = (const float*)d_in[5];
  const float* bv = (const float*)d_in[6];
  const float* Wo = (const float*)d_in[7];
  const float* bo = (const float*)d_in[8];

  char* ws = (char*)d_ws;
  // Overlay plan: [0,8) Xh + [8,14) Wq/k/v-t  (dead after QKV gemm)
  //               [0,16) Ob fp32 (attn..gemmO) overlays them
  //               [16,24) Qb ; [24,32) Kb ; [32,40) Vtb ; [40,42) Wot ;
  //               [42,42.25) Lb
  _Float16* Xh = (_Float16*)(ws);
  _Float16* Wqt = (_Float16*)(ws + (8ull << 20));
  _Float16* Wkt = (_Float16*)(ws + (10ull << 20));
  _Float16* Wvt = (_Float16*)(ws + (12ull << 20));
  float* Ob = (float*)(ws);
  _Float16* Qb = (_Float16*)(ws + (16ull << 20));
  _Float16* Kb = (_Float16*)(ws + (24ull << 20));
  _Float16* Vtb = (_Float16*)(ws + (32ull << 20));
  _Float16* Wot = (_Float16*)(ws + (40ull << 20));
  float* Lb = (float*)(ws + (42ull << 20));

  WtArgs wa{Wq, Wk, Wv, Wo, Wqt, Wkt, Wvt, Wot};
  prep<<<dim3(2048 + 1024), 256, 0, stream>>>(hid, Xh, wa);

  GemmArgs g1{Xh, Wqt, Wkt, Wvt, bq, bk, bv, Qb, Kb, Vtb};
  gemmQKV<<<dim3(Mrows / 128, Ddim / 128, 3), 256, 0, stream>>>(g1);

  hipMemsetAsync(Ob, 0, 16ull << 20, stream);
  hipMemsetAsync(Lb, 0, (size_t)32 * Sdim * sizeof(float), stream);

  attn<<<dim3(2560), 256, 0, stream>>>(Qb, Kb, Vtb, Ob, Lb);

  gemmO<<<dim3(Mrows / 64, Ddim / 128), 256, 0, stream>>>(Ob, Lb, Wot, bo,
                                                          (float*)d_out);
}